// Round 15
// baseline (657.613 us; speedup 1.0000x reference)
//
#include <hip/hip_runtime.h>
#include <stdint.h>

constexpr int Cc   = 256;
constexpr int Kc   = 1024;
constexpr int NLOC = 16 * 56 * 56;      // 50176
constexpr int NB   = 2;
constexpr int NTOT = NB * NLOC;         // 100352
constexpr long long ZQV = (long long)NB * Cc * NLOC;  // 25690112

// screen tiling: one block = 256 rows x 128 codes, K=256 in 4 chunks of 64
constexpr int SR   = 256;
constexpr int SC   = 128;
constexpr int BK   = 64;
constexpr int NCH  = Cc / BK;           // 4
constexpr int NRT  = NTOT / SR;         // 392 row tiles (= 8 XCDs x 49)
constexpr int NSL  = Kc / SC;           // 8
constexpr int SBLK = NRT * NSL;         // 3136

constexpr int   SLOTS = 16;
constexpr float WIN   = 3e-4f;          // validated (absmax idx = 0 at 3e-4)
constexpr float NEG2S = -0.001953125f;  // -2/1024 (exact descale)

constexpr int F1B = NTOT / 256;         // 392
constexpr int RB  = 32;                 // rows per gather block
constexpr int F2B = NTOT / RB;          // 3136

using f16x8 = __attribute__((ext_vector_type(8))) _Float16;
using f32x4 = __attribute__((ext_vector_type(4))) float;
typedef unsigned long long u64;
typedef unsigned int       u32;
typedef unsigned short     u16;

// ---------------------------------------------------------------------------
// numpy-exact helpers (validated, unchanged)
// ---------------------------------------------------------------------------
__device__ __forceinline__ float sqf(float x) {
    float s = x * x;
    asm("" : "+v"(s));
    return s;
}

template <typename Loader>
__device__ __forceinline__ float pw256_sq(Loader ld)
{
    float half[2];
    #pragma unroll
    for (int h = 0; h < 2; ++h) {
        float r[8];
        #pragma unroll
        for (int j = 0; j < 8; ++j) r[j] = sqf(ld(h * 128 + j));
        #pragma unroll
        for (int i = 8; i < 128; i += 8)
            #pragma unroll
            for (int j = 0; j < 8; ++j) r[j] += sqf(ld(h * 128 + i + j));
        half[h] = ((r[0] + r[1]) + (r[2] + r[3])) + ((r[4] + r[5]) + (r[6] + r[7]));
    }
    return half[0] + half[1];
}

__global__ void esq_pw(const float* __restrict__ key, float* __restrict__ esq)
{
    int k = blockIdx.x * 256 + threadIdx.x;
    if (k < Kc) {
        const float* a = key + (size_t)k * Cc;
        esq[k] = pw256_sq([&](int c) { return a[c]; });
    }
}

__device__ __forceinline__ u16 f16b(float x)
{
    _Float16 h = (_Float16)x;   // v_cvt_f16_f32, RNE
    u16 r;
    __builtin_memcpy(&r, &h, 2);
    return r;
}

// split_e: ef16[k][c] = f16(key[k][c] * 1024)  (exact pow-2 scale)
__global__ void split_e(const float* __restrict__ key, u16* __restrict__ ef16)
{
    int i = blockIdx.x * 256 + threadIdx.x;
    if (i < Kc * Cc) ef16[i] = f16b(key[i] * 1024.0f);
}

// split_z: z [B][C][NLOC] f32 -> zf16 [NTOT][C] f16 (+ zt32 f32 copy, + zsq)
__global__ __launch_bounds__(256, 2)
void split_z(const float* __restrict__ z, u16* __restrict__ zf16,
             float* __restrict__ zt32, float* __restrict__ zsq)
{
    __shared__ float t[64][260];
    const int tid = threadIdx.x;
    const int n0  = blockIdx.x * 64;
    const int b   = (n0 >= NLOC) ? 1 : 0;
    const int loc0 = n0 - b * NLOC;
    const float* zb = z + (size_t)b * Cc * NLOC;

    {
        const int n4 = tid & 15;
        #pragma unroll
        for (int it = 0; it < 4; ++it) {
            int c4 = (tid >> 4) + it * 16;
            float4 g0 = *reinterpret_cast<const float4*>(zb + (size_t)(c4 * 4 + 0) * NLOC + loc0 + n4 * 4);
            float4 g1 = *reinterpret_cast<const float4*>(zb + (size_t)(c4 * 4 + 1) * NLOC + loc0 + n4 * 4);
            float4 g2 = *reinterpret_cast<const float4*>(zb + (size_t)(c4 * 4 + 2) * NLOC + loc0 + n4 * 4);
            float4 g3 = *reinterpret_cast<const float4*>(zb + (size_t)(c4 * 4 + 3) * NLOC + loc0 + n4 * 4);
            *reinterpret_cast<float4*>(&t[n4 * 4 + 0][c4 * 4]) = make_float4(g0.x, g1.x, g2.x, g3.x);
            *reinterpret_cast<float4*>(&t[n4 * 4 + 1][c4 * 4]) = make_float4(g0.y, g1.y, g2.y, g3.y);
            *reinterpret_cast<float4*>(&t[n4 * 4 + 2][c4 * 4]) = make_float4(g0.z, g1.z, g2.z, g3.z);
            *reinterpret_cast<float4*>(&t[n4 * 4 + 3][c4 * 4]) = make_float4(g0.w, g1.w, g2.w, g3.w);
        }
    }
    __syncthreads();
    {
        const int row2 = tid >> 5;
        const int ch   = tid & 31;
        #pragma unroll
        for (int rg = 0; rg < 8; ++rg) {
            int row = rg * 8 + row2;
            float4 f0 = *reinterpret_cast<const float4*>(&t[row][ch * 8]);
            float4 f1 = *reinterpret_cast<const float4*>(&t[row][ch * 8 + 4]);
            float xs[8] = {f0.x, f0.y, f0.z, f0.w, f1.x, f1.y, f1.z, f1.w};
            u32 hp[4];
            #pragma unroll
            for (int j = 0; j < 4; ++j)
                hp[j] = (u32)f16b(xs[2 * j]) | ((u32)f16b(xs[2 * j + 1]) << 16);
            size_t o = ((size_t)(n0 + row)) * Cc + ch * 8;
            *reinterpret_cast<uint4*>(zf16 + o) = make_uint4(hp[0], hp[1], hp[2], hp[3]);
            if (zt32) {
                *reinterpret_cast<float4*>(zt32 + o)     = f0;   // bit-exact f32 copies
                *reinterpret_cast<float4*>(zt32 + o + 4) = f1;
            }
        }
    }
    if (tid < 64)
        zsq[n0 + tid] = pw256_sq([&](int c) { return t[tid][c]; });
}

// global -> LDS direct, 16B/lane (dest = uniform base + lane*16)
__device__ __forceinline__ void gload16(const u16* g, u16* lds)
{
    __builtin_amdgcn_global_load_lds(
        (const __attribute__((address_space(1))) u32*)g,
        (__attribute__((address_space(3))) u32*)lds, 16, 0, 0);
}

// ---------------------------------------------------------------------------
// screen: f16 MFMA GEMM, NOW 256x128 tile (2x work per barrier vs R14),
// BK=64, single-buffered, XCD-aware remap. Per-element MFMA sequence is
// unchanged -> d~ bit-identical to R14; emission set identical.
// ---------------------------------------------------------------------------
__global__ __launch_bounds__(256, 3)
void screen(const u16* __restrict__ zf16, const u16* __restrict__ ef16,
            const float* __restrict__ esq, const float* __restrict__ zsq,
            u64* __restrict__ cand, int* __restrict__ cnt)
{
    __shared__ u16  A_lds[SR * BK];    // 32 KB
    __shared__ u16  B_lds[SC * BK];    // 16 KB
    __shared__ float gm[2][SR];        // 2 KB
    __shared__ float esq_s[SC];
    __shared__ float zsq_s[SR];

    const int tid = threadIdx.x;
    const int bid = blockIdx.x;
    // XCD grouping: xcd = bid&7 owns row-tiles [xcd*49, (xcd+1)*49)
    const int q   = bid >> 3;
    const int rt  = (bid & 7) * (NRT / 8) + (q >> 3);
    const int r0  = rt * SR;
    const int k0  = (q & 7) * SC;
    const int wid = tid >> 6, l = tid & 63;
    const int wr  = wid >> 1, wc = wid & 1;   // wave covers 128 rows x 64 cols

    for (int i = tid; i < SC; i += 256) esq_s[i] = esq[k0 + i];
    for (int i = tid; i < SR; i += 256) zsq_s[i] = zsq[r0 + i];

    f32x4 acc[8][4];
    #pragma unroll
    for (int i = 0; i < 8; ++i)
        #pragma unroll
        for (int j = 0; j < 4; ++j)
            acc[i][j] = f32x4{0.f, 0.f, 0.f, 0.f};

    for (int ch = 0; ch < NCH; ++ch) {
        __syncthreads();   // previous chunk consumed (covers esq_s/zsq_s on ch=0)
        {
            const int lr = l >> 3;
            #pragma unroll
            for (int t = 0; t < 8; ++t) {      // A: 256 rows, 8 instrs/wave
                int rowb = wid * 64 + t * 8;
                int row  = rowb + lr;
                int g    = (l & 7) ^ (row & 7);
                gload16(zf16 + (size_t)(r0 + row) * Cc + ch * BK + g * 8,
                        A_lds + rowb * BK);
            }
            #pragma unroll
            for (int t = 0; t < 4; ++t) {      // B: 128 codes, 4 instrs/wave
                int rowb = wid * 32 + t * 8;
                int row  = rowb + lr;
                int g    = (l & 7) ^ (row & 7);
                gload16(ef16 + (size_t)(k0 + row) * Cc + ch * BK + g * 8,
                        B_lds + rowb * BK);
            }
        }
        __syncthreads();   // vmcnt drained

        #pragma unroll
        for (int kk = 0; kk < 2; ++kk) {
            f16x8 af[8], bf[4];
            const int G = kk * 4 + (l >> 4);
            #pragma unroll
            for (int i = 0; i < 8; ++i) {
                int row = wr * 128 + i * 16 + (l & 15);
                int pg  = G ^ (row & 7);
                af[i] = *reinterpret_cast<const f16x8*>(&A_lds[row * BK + pg * 8]);
            }
            #pragma unroll
            for (int j = 0; j < 4; ++j) {
                int col = wc * 64 + j * 16 + (l & 15);
                int pg  = G ^ (col & 7);
                bf[j] = *reinterpret_cast<const f16x8*>(&B_lds[col * BK + pg * 8]);
            }
            #pragma unroll
            for (int i = 0; i < 8; ++i)
                #pragma unroll
                for (int j = 0; j < 4; ++j)
                    acc[i][j] = __builtin_amdgcn_mfma_f32_16x16x32_f16(
                        af[i], bf[j], acc[i][j], 0, 0, 0);
        }
    }

    // ---- epilogue pass 1: f32 slice-min per row ----
    #pragma unroll
    for (int i = 0; i < 8; ++i) {
        #pragma unroll
        for (int r = 0; r < 4; ++r) {
            int rloc = wr * 128 + i * 16 + ((l >> 4) << 2) + r;
            float zq = zsq_s[rloc];
            float mn = 3.4e38f;
            #pragma unroll
            for (int j = 0; j < 4; ++j) {
                int cl = wc * 64 + j * 16 + (l & 15);
                float d = fmaf(NEG2S, acc[i][j][r], zq + esq_s[cl]);
                mn = fminf(mn, d);
            }
            #pragma unroll
            for (int m = 1; m < 16; m <<= 1)
                mn = fminf(mn, __shfl_xor(mn, m, 64));
            if ((l & 15) == 0) gm[wc][rloc] = mn;
        }
    }
    __syncthreads();

    // ---- epilogue pass 2: window emission ----
    #pragma unroll
    for (int i = 0; i < 8; ++i) {
        #pragma unroll
        for (int r = 0; r < 4; ++r) {
            int rloc = wr * 128 + i * 16 + ((l >> 4) << 2) + r;
            float thr = fminf(gm[0][rloc], gm[1][rloc]) + WIN;
            float zq = zsq_s[rloc];
            int rg = r0 + rloc;
            #pragma unroll
            for (int j = 0; j < 4; ++j) {
                int cl = wc * 64 + j * 16 + (l & 15);
                float d = fmaf(NEG2S, acc[i][j][r], zq + esq_s[cl]);
                if (d <= thr) {
                    int slot = atomicAdd(&cnt[rg], 1);
                    if (slot < SLOTS)
                        cand[(size_t)rg * SLOTS + slot] =
                            ((u64)__float_as_uint(d) << 32) | (u32)(k0 + cl);
                }
            }
        }
    }
}

// ---------------------------------------------------------------------------
// resolve_pick: thread per row; pick best candidate; emit dbest (= loss term);
// push ambiguous/overflow rows to worklist.
// ---------------------------------------------------------------------------
__global__ __launch_bounds__(256)
void resolve_pick(const u64* __restrict__ cand, const int* __restrict__ cnt,
                  int* __restrict__ idxw, float* __restrict__ dbest,
                  float* __restrict__ out,
                  int* __restrict__ wl, int* __restrict__ wcount)
{
    const int p = blockIdx.x * 256 + threadIdx.x;
    const int c = cnt[p];
    const int n = (c < SLOTS) ? c : SLOTS;
    u64 best = 0xFFFFFFFFFFFFFFFFull;
    for (int s = 0; s < n; ++s) {
        u64 v = cand[(size_t)p * SLOTS + s];
        if (v < best) best = v;
    }
    const float db = __uint_as_float((u32)(best >> 32));

    bool needs = (c > SLOTS);
    if (!needs) {
        int namb = 0;
        for (int s = 0; s < n; ++s) {
            float dv = __uint_as_float((u32)(cand[(size_t)p * SLOTS + s] >> 32));
            namb += (dv <= db + WIN) ? 1 : 0;
        }
        needs = (namb > 1);
    }
    if (needs) wl[atomicAdd(wcount, 1)] = p;

    idxw[p] = (int)(u32)best;
    dbest[p] = db;                      // loss term: d == ||key[k]-z||^2
    out[ZQV + p] = (float)(u32)best;
}

// ---------------------------------------------------------------------------
// rescore: np-exact re-evaluation of worklist rows using contiguous zt32 rows.
// ---------------------------------------------------------------------------
__global__ __launch_bounds__(256)
void rescore(const float* __restrict__ zt32, const float* __restrict__ key,
             const float* __restrict__ esq, const float* __restrict__ zsq,
             const u64* __restrict__ cand, const int* __restrict__ cnt,
             const int* __restrict__ wcount, const int* __restrict__ wl,
             int* __restrict__ idxw, float* __restrict__ dbest,
             float* __restrict__ out)
{
    const int i = blockIdx.x * 256 + threadIdx.x;
    if (i >= *wcount) return;
    const int p = wl[i];
    const float* zr = zt32 + (size_t)p * Cc;   // bit-exact f32 z row
    const float zq = zsq[p];
    const int c = cnt[p];
    u64 bb = 0xFFFFFFFFFFFFFFFFull;

    if (c > SLOTS) {
        for (int k = 0; k < Kc; ++k) {
            const float* kr = key + (size_t)k * Cc;
            float m = 0.f;
            for (int cc = 0; cc < Cc; ++cc)
                m = fmaf(zr[cc], kr[cc], m);
            float d = fmaf(-2.0f, m, zq + esq[k]);
            u64 pk = ((u64)__float_as_uint(d) << 32) | (u32)k;
            if (pk < bb) bb = pk;
        }
    } else {
        u64 best = 0xFFFFFFFFFFFFFFFFull;
        for (int s = 0; s < c; ++s) {
            u64 v = cand[(size_t)p * SLOTS + s];
            if (v < best) best = v;
        }
        const float db = __uint_as_float((u32)(best >> 32));
        for (int s = 0; s < c; ++s) {
            u64 v = cand[(size_t)p * SLOTS + s];
            float dv = __uint_as_float((u32)(v >> 32));
            if (dv <= db + WIN) {
                int k = (int)(u32)v;
                const float* kr = key + (size_t)k * Cc;
                float m = 0.f;
                for (int cc = 0; cc < Cc; ++cc)
                    m = fmaf(zr[cc], kr[cc], m);
                float d = fmaf(-2.0f, m, zq + esq[k]);
                u64 pk = ((u64)__float_as_uint(d) << 32) | (u32)k;
                if (pk < bb) bb = pk;
            }
        }
    }
    idxw[p] = (int)(u32)bb;
    dbest[p] = __uint_as_float((u32)(bb >> 32));
    out[ZQV + p] = (float)(u32)bb;
}

// ---------------------------------------------------------------------------
// resolve_fallback: monolithic path (strided z reads) if ws too small for zt32
// ---------------------------------------------------------------------------
__global__ __launch_bounds__(256)
void resolve_fallback(const float* __restrict__ z, const float* __restrict__ key,
                      const float* __restrict__ esq, const float* __restrict__ zsq,
                      const u64* __restrict__ cand, const int* __restrict__ cnt,
                      float* __restrict__ out, int* __restrict__ idxw,
                      float* __restrict__ dbest)
{
    const int p   = blockIdx.x * 256 + threadIdx.x;
    const int b   = (p >= NLOC) ? 1 : 0;
    const int loc = p - b * NLOC;
    const float* zb = z + (size_t)b * Cc * NLOC;

    const int c = cnt[p];
    const int n = (c < SLOTS) ? c : SLOTS;
    u64 best = 0xFFFFFFFFFFFFFFFFull;
    for (int s = 0; s < n; ++s) {
        u64 v = cand[(size_t)p * SLOTS + s];
        if (v < best) best = v;
    }
    u64 sel = best;
    const float db = __uint_as_float((u32)(best >> 32));

    if (c > SLOTS) {
        u64 bb = 0xFFFFFFFFFFFFFFFFull;
        for (int k = 0; k < Kc; ++k) {
            const float* kr = key + (size_t)k * Cc;
            float m = 0.f;
            for (int cc = 0; cc < Cc; ++cc)
                m = fmaf(zb[(size_t)cc * NLOC + loc], kr[cc], m);
            float d = fmaf(-2.0f, m, zsq[p] + esq[k]);
            u64 pk = ((u64)__float_as_uint(d) << 32) | (u32)k;
            if (pk < bb) bb = pk;
        }
        sel = bb;
    } else {
        int namb = 0;
        for (int s = 0; s < n; ++s) {
            float dv = __uint_as_float((u32)(cand[(size_t)p * SLOTS + s] >> 32));
            namb += (dv <= db + WIN) ? 1 : 0;
        }
        if (namb > 1) {
            u64 bb = 0xFFFFFFFFFFFFFFFFull;
            for (int s = 0; s < n; ++s) {
                u64 v = cand[(size_t)p * SLOTS + s];
                float dv = __uint_as_float((u32)(v >> 32));
                if (dv <= db + WIN) {
                    int k = (int)(u32)v;
                    const float* kr = key + (size_t)k * Cc;
                    float m = 0.f;
                    for (int cc = 0; cc < Cc; ++cc)
                        m = fmaf(zb[(size_t)cc * NLOC + loc], kr[cc], m);
                    float d = fmaf(-2.0f, m, zsq[p] + esq[k]);
                    u64 pk = ((u64)__float_as_uint(d) << 32) | (u32)k;
                    if (pk < bb) bb = pk;
                }
            }
            sel = bb;
        }
    }
    idxw[p] = (int)(u32)sel;
    dbest[p] = __uint_as_float((u32)(sel >> 32));
    out[ZQV + p] = (float)(u32)sel;
}

// ---------------------------------------------------------------------------
// gather: val-row gather + z_q_value write only (loss now comes from dbest).
// ---------------------------------------------------------------------------
__global__ __launch_bounds__(256)
void gather(const float* __restrict__ val, const int* __restrict__ idxw,
            float* __restrict__ out)
{
    __shared__ float rowbuf[RB][261];
    __shared__ int   idx_sh[RB];
    const int tid = threadIdx.x, blk = blockIdx.x;
    const int wid = tid >> 6, l = tid & 63;
    const int p0  = blk * RB;
    const int b   = (p0 >= NLOC) ? 1 : 0;
    const int loc0 = p0 - b * NLOC;

    if (tid < RB) idx_sh[tid] = idxw[p0 + tid];
    __syncthreads();

    #pragma unroll
    for (int i = 0; i < RB / 4; ++i) {
        int row = wid * (RB / 4) + i;
        float4 v = *reinterpret_cast<const float4*>(val + (size_t)idx_sh[row] * Cc + l * 4);
        *reinterpret_cast<float4*>(&rowbuf[row][l * 4]) = v;
    }
    __syncthreads();

    const int nq = l & 7;
    #pragma unroll
    for (int it = 0; it < 8; ++it) {
        int cc = (l >> 3) + 8 * it + 64 * wid;
        float4 v = make_float4(rowbuf[nq * 4 + 0][cc], rowbuf[nq * 4 + 1][cc],
                               rowbuf[nq * 4 + 2][cc], rowbuf[nq * 4 + 3][cc]);
        *reinterpret_cast<float4*>(
            out + ((size_t)b * Cc + cc) * NLOC + loc0 + nq * 4) = v;
    }
}

// fin: loss = 1.25 * sum(dbest) / (NTOT*C)   (d == ||key[idx]-z||^2; f64 sum)
__global__ void fin_kernel(const float* __restrict__ dbest, float* __restrict__ out_loss)
{
    __shared__ double sh[256];
    double s = 0.0;
    for (int i = threadIdx.x; i < NTOT; i += 256) s += (double)dbest[i];
    sh[threadIdx.x] = s;
    __syncthreads();
    for (int st = 128; st > 0; st >>= 1) {
        if (threadIdx.x < st) sh[threadIdx.x] += sh[threadIdx.x + st];
        __syncthreads();
    }
    if (threadIdx.x == 0)
        out_loss[0] = (float)(1.25 * sh[0] / (double)((long long)NTOT * Cc));
}

// ---------------------------------------------------------------------------
extern "C" void kernel_launch(void* const* d_in, const int* in_sizes, int n_in,
                              void* d_out, int out_size, void* d_ws, size_t ws_size,
                              hipStream_t stream)
{
    const float* z   = (const float*)d_in[0];
    const float* key = (const float*)d_in[1];
    const float* val = (const float*)d_in[2];
    float* out = (float*)d_out;

    // zf16 scratch lives in the z_q_value output region (dead before gather)
    u16* zf16 = (u16*)d_out;

    char* w = (char*)d_ws;
    u16*    ef16    = (u16*)w;                 w += (size_t)Kc * Cc * 2;        // 512 KB
    u64*    cand    = (u64*)w;                 w += (size_t)NTOT * SLOTS * 8;   // 12.85 MB
    int*    cnt     = (int*)w;                 w += (size_t)NTOT * 4;           // 401 KB
    int*    wcount  = (int*)w;                 w += 16;
    int*    idxw    = (int*)w;                 w += (size_t)NTOT * 4;
    int*    wl      = (int*)w;                 w += (size_t)NTOT * 4;
    float*  dbest   = (float*)w;               w += (size_t)NTOT * 4;
    float*  esq     = (float*)w;               w += (size_t)Kc * 4;
    float*  zsq     = (float*)w;               w += (size_t)NTOT * 4;
    float*  zt32    = (float*)w;
    size_t  need_big = (size_t)(w - (char*)d_ws) + (size_t)NTOT * Cc * 4;
    const bool big = ws_size >= need_big;

    hipMemsetAsync(cnt, 0, (size_t)NTOT * 4 + 16, stream);  // cnt + wcount
    hipLaunchKernelGGL(esq_pw, dim3((Kc + 255) / 256), dim3(256), 0, stream, key, esq);
    hipLaunchKernelGGL(split_e, dim3((Kc * Cc + 255) / 256), dim3(256), 0, stream, key, ef16);
    hipLaunchKernelGGL(split_z, dim3(NTOT / 64), dim3(256), 0, stream, z, zf16,
                       big ? zt32 : (float*)nullptr, zsq);
    hipLaunchKernelGGL(screen, dim3(SBLK), dim3(256), 0, stream,
                       zf16, ef16, esq, zsq, cand, cnt);
    if (big) {
        hipLaunchKernelGGL(resolve_pick, dim3(F1B), dim3(256), 0, stream,
                           cand, cnt, idxw, dbest, out, wl, wcount);
        hipLaunchKernelGGL(rescore, dim3(F1B), dim3(256), 0, stream,
                           zt32, key, esq, zsq, cand, cnt, wcount, wl, idxw, dbest, out);
    } else {
        hipLaunchKernelGGL(resolve_fallback, dim3(F1B), dim3(256), 0, stream,
                           z, key, esq, zsq, cand, cnt, out, idxw, dbest);
    }
    hipLaunchKernelGGL(gather, dim3(F2B), dim3(256), 0, stream, val, idxw, out);
    hipLaunchKernelGGL(fin_kernel, dim3(1), dim3(256), 0, stream, dbest, out + ZQV + NTOT);
}

// Round 16
// 378.623 us; speedup vs baseline: 1.7369x; 1.7369x over previous
//
#include <hip/hip_runtime.h>
#include <stdint.h>

constexpr int Cc   = 256;
constexpr int Kc   = 1024;
constexpr int NLOC = 16 * 56 * 56;      // 50176
constexpr int NB   = 2;
constexpr int NTOT = NB * NLOC;         // 100352
constexpr long long ZQV = (long long)NB * Cc * NLOC;  // 25690112

// screen tiling: one block = 128 rows x 128 codes, K=256 in 4 chunks of 64
// (R14-validated geometry: 34.8 KB LDS, 4 blocks/CU, MfmaUtil ~13%)
constexpr int SR   = 128;
constexpr int SC   = 128;
constexpr int BK   = 64;
constexpr int NCH  = Cc / BK;           // 4
constexpr int NRT  = NTOT / SR;         // 784 row tiles (= 8 XCDs x 98)
constexpr int NSL  = Kc / SC;           // 8
constexpr int SBLK = NRT * NSL;         // 6272

constexpr int   SLOTS = 16;
constexpr float WIN   = 3e-4f;          // validated (absmax idx = 0 at 3e-4)
constexpr float NEG2S = -0.001953125f;  // -2/1024 (exact descale)

constexpr int F1B = NTOT / 256;         // 392
constexpr int RB  = 32;                 // rows per gather block
constexpr int F2B = NTOT / RB;          // 3136
constexpr int DSB = NTOT / 256;         // 392 dsum blocks

using f16x8 = __attribute__((ext_vector_type(8))) _Float16;
using f32x4 = __attribute__((ext_vector_type(4))) float;
typedef unsigned long long u64;
typedef unsigned int       u32;
typedef unsigned short     u16;

// ---------------------------------------------------------------------------
// numpy-exact helpers (validated, unchanged)
// ---------------------------------------------------------------------------
__device__ __forceinline__ float sqf(float x) {
    float s = x * x;
    asm("" : "+v"(s));
    return s;
}

template <typename Loader>
__device__ __forceinline__ float pw256_sq(Loader ld)
{
    float half[2];
    #pragma unroll
    for (int h = 0; h < 2; ++h) {
        float r[8];
        #pragma unroll
        for (int j = 0; j < 8; ++j) r[j] = sqf(ld(h * 128 + j));
        #pragma unroll
        for (int i = 8; i < 128; i += 8)
            #pragma unroll
            for (int j = 0; j < 8; ++j) r[j] += sqf(ld(h * 128 + i + j));
        half[h] = ((r[0] + r[1]) + (r[2] + r[3])) + ((r[4] + r[5]) + (r[6] + r[7]));
    }
    return half[0] + half[1];
}

__global__ void esq_pw(const float* __restrict__ key, float* __restrict__ esq)
{
    int k = blockIdx.x * 256 + threadIdx.x;
    if (k < Kc) {
        const float* a = key + (size_t)k * Cc;
        esq[k] = pw256_sq([&](int c) { return a[c]; });
    }
}

__device__ __forceinline__ u16 f16b(float x)
{
    _Float16 h = (_Float16)x;   // v_cvt_f16_f32, RNE
    u16 r;
    __builtin_memcpy(&r, &h, 2);
    return r;
}

// split_e: ef16[k][c] = f16(key[k][c] * 1024)  (exact pow-2 scale)
__global__ void split_e(const float* __restrict__ key, u16* __restrict__ ef16)
{
    int i = blockIdx.x * 256 + threadIdx.x;
    if (i < Kc * Cc) ef16[i] = f16b(key[i] * 1024.0f);
}

// split_z: z [B][C][NLOC] f32 -> zf16 [NTOT][C] f16 (+ zt32 f32 copy, + zsq)
__global__ __launch_bounds__(256, 2)
void split_z(const float* __restrict__ z, u16* __restrict__ zf16,
             float* __restrict__ zt32, float* __restrict__ zsq)
{
    __shared__ float t[64][260];
    const int tid = threadIdx.x;
    const int n0  = blockIdx.x * 64;
    const int b   = (n0 >= NLOC) ? 1 : 0;
    const int loc0 = n0 - b * NLOC;
    const float* zb = z + (size_t)b * Cc * NLOC;

    {
        const int n4 = tid & 15;
        #pragma unroll
        for (int it = 0; it < 4; ++it) {
            int c4 = (tid >> 4) + it * 16;
            float4 g0 = *reinterpret_cast<const float4*>(zb + (size_t)(c4 * 4 + 0) * NLOC + loc0 + n4 * 4);
            float4 g1 = *reinterpret_cast<const float4*>(zb + (size_t)(c4 * 4 + 1) * NLOC + loc0 + n4 * 4);
            float4 g2 = *reinterpret_cast<const float4*>(zb + (size_t)(c4 * 4 + 2) * NLOC + loc0 + n4 * 4);
            float4 g3 = *reinterpret_cast<const float4*>(zb + (size_t)(c4 * 4 + 3) * NLOC + loc0 + n4 * 4);
            *reinterpret_cast<float4*>(&t[n4 * 4 + 0][c4 * 4]) = make_float4(g0.x, g1.x, g2.x, g3.x);
            *reinterpret_cast<float4*>(&t[n4 * 4 + 1][c4 * 4]) = make_float4(g0.y, g1.y, g2.y, g3.y);
            *reinterpret_cast<float4*>(&t[n4 * 4 + 2][c4 * 4]) = make_float4(g0.z, g1.z, g2.z, g3.z);
            *reinterpret_cast<float4*>(&t[n4 * 4 + 3][c4 * 4]) = make_float4(g0.w, g1.w, g2.w, g3.w);
        }
    }
    __syncthreads();
    {
        const int row2 = tid >> 5;
        const int ch   = tid & 31;
        #pragma unroll
        for (int rg = 0; rg < 8; ++rg) {
            int row = rg * 8 + row2;
            float4 f0 = *reinterpret_cast<const float4*>(&t[row][ch * 8]);
            float4 f1 = *reinterpret_cast<const float4*>(&t[row][ch * 8 + 4]);
            float xs[8] = {f0.x, f0.y, f0.z, f0.w, f1.x, f1.y, f1.z, f1.w};
            u32 hp[4];
            #pragma unroll
            for (int j = 0; j < 4; ++j)
                hp[j] = (u32)f16b(xs[2 * j]) | ((u32)f16b(xs[2 * j + 1]) << 16);
            size_t o = ((size_t)(n0 + row)) * Cc + ch * 8;
            *reinterpret_cast<uint4*>(zf16 + o) = make_uint4(hp[0], hp[1], hp[2], hp[3]);
            if (zt32) {
                *reinterpret_cast<float4*>(zt32 + o)     = f0;   // bit-exact f32 copies
                *reinterpret_cast<float4*>(zt32 + o + 4) = f1;
            }
        }
    }
    if (tid < 64)
        zsq[n0 + tid] = pw256_sq([&](int c) { return t[tid][c]; });
}

// global -> LDS direct, 16B/lane (dest = uniform base + lane*16)
__device__ __forceinline__ void gload16(const u16* g, u16* lds)
{
    __builtin_amdgcn_global_load_lds(
        (const __attribute__((address_space(1))) u32*)g,
        (__attribute__((address_space(3))) u32*)lds, 16, 0, 0);
}

// ---------------------------------------------------------------------------
// screen: f16 MFMA GEMM — EXACT R14 geometry (128x128, BK=64, single-buffer,
// 4 blocks/CU, XCD-aware remap, f32 slice-min epilogue). R15's 256-row tile
// reverted: 212 unified regs -> 2 waves/SIMD, MfmaUtil 5.9%, FETCH 4.6x.
// ---------------------------------------------------------------------------
__global__ __launch_bounds__(256, 4)
void screen(const u16* __restrict__ zf16, const u16* __restrict__ ef16,
            const float* __restrict__ esq, const float* __restrict__ zsq,
            u64* __restrict__ cand, int* __restrict__ cnt)
{
    __shared__ u16  A_lds[SR * BK];    // 16 KB
    __shared__ u16  B_lds[SC * BK];    // 16 KB
    __shared__ float gm[2][SR];        // 1 KB
    __shared__ float esq_s[SC];
    __shared__ float zsq_s[SR];

    const int tid = threadIdx.x;
    const int bid = blockIdx.x;
    // XCD grouping: xcd = bid&7 owns row-tiles [xcd*98, (xcd+1)*98)
    const int q   = bid >> 3;
    const int rt  = (bid & 7) * (NRT / 8) + (q >> 3);
    const int r0  = rt * SR;
    const int k0  = (q & 7) * SC;
    const int wid = tid >> 6, l = tid & 63;
    const int wr  = wid >> 1, wc = wid & 1;

    for (int i = tid; i < SC; i += 256) esq_s[i] = esq[k0 + i];
    for (int i = tid; i < SR; i += 256) zsq_s[i] = zsq[r0 + i];

    f32x4 acc[4][4];
    #pragma unroll
    for (int i = 0; i < 4; ++i)
        #pragma unroll
        for (int j = 0; j < 4; ++j)
            acc[i][j] = f32x4{0.f, 0.f, 0.f, 0.f};

    for (int ch = 0; ch < NCH; ++ch) {
        __syncthreads();   // previous chunk consumed (covers esq_s/zsq_s on ch=0)
        {
            const int lr = l >> 3;
            #pragma unroll
            for (int t = 0; t < 4; ++t) {
                int rowb = wid * 32 + t * 8;
                int row  = rowb + lr;
                int g    = (l & 7) ^ (row & 7);
                gload16(zf16 + (size_t)(r0 + row) * Cc + ch * BK + g * 8,
                        A_lds + rowb * BK);
                gload16(ef16 + (size_t)(k0 + row) * Cc + ch * BK + g * 8,
                        B_lds + rowb * BK);
            }
        }
        __syncthreads();   // vmcnt drained

        #pragma unroll
        for (int kk = 0; kk < 2; ++kk) {
            f16x8 af[4], bf[4];
            const int G = kk * 4 + (l >> 4);
            #pragma unroll
            for (int i = 0; i < 4; ++i) {
                int row = wr * 64 + i * 16 + (l & 15);
                int pg  = G ^ (row & 7);
                af[i] = *reinterpret_cast<const f16x8*>(&A_lds[row * BK + pg * 8]);
            }
            #pragma unroll
            for (int j = 0; j < 4; ++j) {
                int col = wc * 64 + j * 16 + (l & 15);
                int pg  = G ^ (col & 7);
                bf[j] = *reinterpret_cast<const f16x8*>(&B_lds[col * BK + pg * 8]);
            }
            #pragma unroll
            for (int i = 0; i < 4; ++i)
                #pragma unroll
                for (int j = 0; j < 4; ++j)
                    acc[i][j] = __builtin_amdgcn_mfma_f32_16x16x32_f16(
                        af[i], bf[j], acc[i][j], 0, 0, 0);
        }
    }

    // ---- epilogue pass 1: f32 slice-min per row ----
    #pragma unroll
    for (int i = 0; i < 4; ++i) {
        #pragma unroll
        for (int r = 0; r < 4; ++r) {
            int rloc = wr * 64 + i * 16 + ((l >> 4) << 2) + r;
            float zq = zsq_s[rloc];
            float mn = 3.4e38f;
            #pragma unroll
            for (int j = 0; j < 4; ++j) {
                int cl = wc * 64 + j * 16 + (l & 15);
                float d = fmaf(NEG2S, acc[i][j][r], zq + esq_s[cl]);
                mn = fminf(mn, d);
            }
            #pragma unroll
            for (int m = 1; m < 16; m <<= 1)
                mn = fminf(mn, __shfl_xor(mn, m, 64));
            if ((l & 15) == 0) gm[wc][rloc] = mn;
        }
    }
    __syncthreads();

    // ---- epilogue pass 2: window emission ----
    #pragma unroll
    for (int i = 0; i < 4; ++i) {
        #pragma unroll
        for (int r = 0; r < 4; ++r) {
            int rloc = wr * 64 + i * 16 + ((l >> 4) << 2) + r;
            float thr = fminf(gm[0][rloc], gm[1][rloc]) + WIN;
            float zq = zsq_s[rloc];
            int rg = r0 + rloc;
            #pragma unroll
            for (int j = 0; j < 4; ++j) {
                int cl = wc * 64 + j * 16 + (l & 15);
                float d = fmaf(NEG2S, acc[i][j][r], zq + esq_s[cl]);
                if (d <= thr) {
                    int slot = atomicAdd(&cnt[rg], 1);
                    if (slot < SLOTS)
                        cand[(size_t)rg * SLOTS + slot] =
                            ((u64)__float_as_uint(d) << 32) | (u32)(k0 + cl);
                }
            }
        }
    }
}

// ---------------------------------------------------------------------------
// resolve_pick: thread per row; best candidate + dbest (= loss term);
// ambiguous/overflow rows -> worklist.
// ---------------------------------------------------------------------------
__global__ __launch_bounds__(256)
void resolve_pick(const u64* __restrict__ cand, const int* __restrict__ cnt,
                  int* __restrict__ idxw, float* __restrict__ dbest,
                  float* __restrict__ out,
                  int* __restrict__ wl, int* __restrict__ wcount)
{
    const int p = blockIdx.x * 256 + threadIdx.x;
    const int c = cnt[p];
    const int n = (c < SLOTS) ? c : SLOTS;
    u64 best = 0xFFFFFFFFFFFFFFFFull;
    for (int s = 0; s < n; ++s) {
        u64 v = cand[(size_t)p * SLOTS + s];
        if (v < best) best = v;
    }
    const float db = __uint_as_float((u32)(best >> 32));

    bool needs = (c > SLOTS);
    if (!needs) {
        int namb = 0;
        for (int s = 0; s < n; ++s) {
            float dv = __uint_as_float((u32)(cand[(size_t)p * SLOTS + s] >> 32));
            namb += (dv <= db + WIN) ? 1 : 0;
        }
        needs = (namb > 1);
    }
    if (needs) wl[atomicAdd(wcount, 1)] = p;

    idxw[p] = (int)(u32)best;
    dbest[p] = db;                      // d == ||key[k]-z||^2 (validated R15)
    out[ZQV + p] = (float)(u32)best;
}

// ---------------------------------------------------------------------------
// rescore: np-exact re-evaluation of worklist rows using contiguous zt32 rows.
// ---------------------------------------------------------------------------
__global__ __launch_bounds__(256)
void rescore(const float* __restrict__ zt32, const float* __restrict__ key,
             const float* __restrict__ esq, const float* __restrict__ zsq,
             const u64* __restrict__ cand, const int* __restrict__ cnt,
             const int* __restrict__ wcount, const int* __restrict__ wl,
             int* __restrict__ idxw, float* __restrict__ dbest,
             float* __restrict__ out)
{
    const int i = blockIdx.x * 256 + threadIdx.x;
    if (i >= *wcount) return;
    const int p = wl[i];
    const float* zr = zt32 + (size_t)p * Cc;   // bit-exact f32 z row
    const float zq = zsq[p];
    const int c = cnt[p];
    u64 bb = 0xFFFFFFFFFFFFFFFFull;

    if (c > SLOTS) {
        for (int k = 0; k < Kc; ++k) {
            const float* kr = key + (size_t)k * Cc;
            float m = 0.f;
            for (int cc = 0; cc < Cc; ++cc)
                m = fmaf(zr[cc], kr[cc], m);
            float d = fmaf(-2.0f, m, zq + esq[k]);
            u64 pk = ((u64)__float_as_uint(d) << 32) | (u32)k;
            if (pk < bb) bb = pk;
        }
    } else {
        u64 best = 0xFFFFFFFFFFFFFFFFull;
        for (int s = 0; s < c; ++s) {
            u64 v = cand[(size_t)p * SLOTS + s];
            if (v < best) best = v;
        }
        const float db = __uint_as_float((u32)(best >> 32));
        for (int s = 0; s < c; ++s) {
            u64 v = cand[(size_t)p * SLOTS + s];
            float dv = __uint_as_float((u32)(v >> 32));
            if (dv <= db + WIN) {
                int k = (int)(u32)v;
                const float* kr = key + (size_t)k * Cc;
                float m = 0.f;
                for (int cc = 0; cc < Cc; ++cc)
                    m = fmaf(zr[cc], kr[cc], m);
                float d = fmaf(-2.0f, m, zq + esq[k]);
                u64 pk = ((u64)__float_as_uint(d) << 32) | (u32)k;
                if (pk < bb) bb = pk;
            }
        }
    }
    idxw[p] = (int)(u32)bb;
    dbest[p] = __uint_as_float((u32)(bb >> 32));
    out[ZQV + p] = (float)(u32)bb;
}

// ---------------------------------------------------------------------------
// resolve_fallback: monolithic path (strided z reads) if ws too small for zt32
// ---------------------------------------------------------------------------
__global__ __launch_bounds__(256)
void resolve_fallback(const float* __restrict__ z, const float* __restrict__ key,
                      const float* __restrict__ esq, const float* __restrict__ zsq,
                      const u64* __restrict__ cand, const int* __restrict__ cnt,
                      float* __restrict__ out, int* __restrict__ idxw,
                      float* __restrict__ dbest)
{
    const int p   = blockIdx.x * 256 + threadIdx.x;
    const int b   = (p >= NLOC) ? 1 : 0;
    const int loc = p - b * NLOC;
    const float* zb = z + (size_t)b * Cc * NLOC;

    const int c = cnt[p];
    const int n = (c < SLOTS) ? c : SLOTS;
    u64 best = 0xFFFFFFFFFFFFFFFFull;
    for (int s = 0; s < n; ++s) {
        u64 v = cand[(size_t)p * SLOTS + s];
        if (v < best) best = v;
    }
    u64 sel = best;
    const float db = __uint_as_float((u32)(best >> 32));

    if (c > SLOTS) {
        u64 bb = 0xFFFFFFFFFFFFFFFFull;
        for (int k = 0; k < Kc; ++k) {
            const float* kr = key + (size_t)k * Cc;
            float m = 0.f;
            for (int cc = 0; cc < Cc; ++cc)
                m = fmaf(zb[(size_t)cc * NLOC + loc], kr[cc], m);
            float d = fmaf(-2.0f, m, zsq[p] + esq[k]);
            u64 pk = ((u64)__float_as_uint(d) << 32) | (u32)k;
            if (pk < bb) bb = pk;
        }
        sel = bb;
    } else {
        int namb = 0;
        for (int s = 0; s < n; ++s) {
            float dv = __uint_as_float((u32)(cand[(size_t)p * SLOTS + s] >> 32));
            namb += (dv <= db + WIN) ? 1 : 0;
        }
        if (namb > 1) {
            u64 bb = 0xFFFFFFFFFFFFFFFFull;
            for (int s = 0; s < n; ++s) {
                u64 v = cand[(size_t)p * SLOTS + s];
                float dv = __uint_as_float((u32)(v >> 32));
                if (dv <= db + WIN) {
                    int k = (int)(u32)v;
                    const float* kr = key + (size_t)k * Cc;
                    float m = 0.f;
                    for (int cc = 0; cc < Cc; ++cc)
                        m = fmaf(zb[(size_t)cc * NLOC + loc], kr[cc], m);
                    float d = fmaf(-2.0f, m, zsq[p] + esq[k]);
                    u64 pk = ((u64)__float_as_uint(d) << 32) | (u32)k;
                    if (pk < bb) bb = pk;
                }
            }
            sel = bb;
        }
    }
    idxw[p] = (int)(u32)sel;
    dbest[p] = __uint_as_float((u32)(sel >> 32));
    out[ZQV + p] = (float)(u32)sel;
}

// ---------------------------------------------------------------------------
// gather: val-row gather + z_q_value write only (loss from dbest).
// ---------------------------------------------------------------------------
__global__ __launch_bounds__(256)
void gather(const float* __restrict__ val, const int* __restrict__ idxw,
            float* __restrict__ out)
{
    __shared__ float rowbuf[RB][261];
    __shared__ int   idx_sh[RB];
    const int tid = threadIdx.x, blk = blockIdx.x;
    const int wid = tid >> 6, l = tid & 63;
    const int p0  = blk * RB;
    const int b   = (p0 >= NLOC) ? 1 : 0;
    const int loc0 = p0 - b * NLOC;

    if (tid < RB) idx_sh[tid] = idxw[p0 + tid];
    __syncthreads();

    #pragma unroll
    for (int i = 0; i < RB / 4; ++i) {
        int row = wid * (RB / 4) + i;
        float4 v = *reinterpret_cast<const float4*>(val + (size_t)idx_sh[row] * Cc + l * 4);
        *reinterpret_cast<float4*>(&rowbuf[row][l * 4]) = v;
    }
    __syncthreads();

    const int nq = l & 7;
    #pragma unroll
    for (int it = 0; it < 8; ++it) {
        int cc = (l >> 3) + 8 * it + 64 * wid;
        float4 v = make_float4(rowbuf[nq * 4 + 0][cc], rowbuf[nq * 4 + 1][cc],
                               rowbuf[nq * 4 + 2][cc], rowbuf[nq * 4 + 3][cc]);
        *reinterpret_cast<float4*>(
            out + ((size_t)b * Cc + cc) * NLOC + loc0 + nq * 4) = v;
    }
}

// ---------------------------------------------------------------------------
// dsum: 392 blocks x 256 threads -> f64 partials (deterministic). Fixes R15's
// single-block fin (392 serial iters on one CU ~= the 75 µs regression).
// ---------------------------------------------------------------------------
__global__ __launch_bounds__(256)
void dsum(const float* __restrict__ dbest, double* __restrict__ partial)
{
    __shared__ double wred[4];
    const int tid = threadIdx.x;
    double s = (double)dbest[blockIdx.x * 256 + tid];
    for (int off = 32; off > 0; off >>= 1) s += __shfl_down(s, off);
    if ((tid & 63) == 0) wred[tid >> 6] = s;
    __syncthreads();
    if (tid == 0) partial[blockIdx.x] = wred[0] + wred[1] + wred[2] + wred[3];
}

__global__ void fin_kernel(const double* __restrict__ partial, float* __restrict__ out_loss)
{
    __shared__ double sh[256];
    double s = 0.0;
    for (int i = threadIdx.x; i < DSB; i += 256) s += partial[i];
    sh[threadIdx.x] = s;
    __syncthreads();
    for (int st = 128; st > 0; st >>= 1) {
        if (threadIdx.x < st) sh[threadIdx.x] += sh[threadIdx.x + st];
        __syncthreads();
    }
    if (threadIdx.x == 0)
        out_loss[0] = (float)(1.25 * sh[0] / (double)((long long)NTOT * Cc));
}

// ---------------------------------------------------------------------------
extern "C" void kernel_launch(void* const* d_in, const int* in_sizes, int n_in,
                              void* d_out, int out_size, void* d_ws, size_t ws_size,
                              hipStream_t stream)
{
    const float* z   = (const float*)d_in[0];
    const float* key = (const float*)d_in[1];
    const float* val = (const float*)d_in[2];
    float* out = (float*)d_out;

    // zf16 scratch lives in the z_q_value output region (dead before gather)
    u16* zf16 = (u16*)d_out;

    char* w = (char*)d_ws;
    u16*    ef16    = (u16*)w;                 w += (size_t)Kc * Cc * 2;        // 512 KB
    u64*    cand    = (u64*)w;                 w += (size_t)NTOT * SLOTS * 8;   // 12.85 MB
    int*    cnt     = (int*)w;                 w += (size_t)NTOT * 4;           // 401 KB
    int*    wcount  = (int*)w;                 w += 16;
    int*    idxw    = (int*)w;                 w += (size_t)NTOT * 4;
    int*    wl      = (int*)w;                 w += (size_t)NTOT * 4;
    float*  dbest   = (float*)w;               w += (size_t)NTOT * 4;
    double* partial = (double*)w;              w += (size_t)DSB * 8;
    float*  esq     = (float*)w;               w += (size_t)Kc * 4;
    float*  zsq     = (float*)w;               w += (size_t)NTOT * 4;
    float*  zt32    = (float*)w;
    size_t  need_big = (size_t)(w - (char*)d_ws) + (size_t)NTOT * Cc * 4;
    const bool big = ws_size >= need_big;

    hipMemsetAsync(cnt, 0, (size_t)NTOT * 4 + 16, stream);  // cnt + wcount
    hipLaunchKernelGGL(esq_pw, dim3((Kc + 255) / 256), dim3(256), 0, stream, key, esq);
    hipLaunchKernelGGL(split_e, dim3((Kc * Cc + 255) / 256), dim3(256), 0, stream, key, ef16);
    hipLaunchKernelGGL(split_z, dim3(NTOT / 64), dim3(256), 0, stream, z, zf16,
                       big ? zt32 : (float*)nullptr, zsq);
    hipLaunchKernelGGL(screen, dim3(SBLK), dim3(256), 0, stream,
                       zf16, ef16, esq, zsq, cand, cnt);
    if (big) {
        hipLaunchKernelGGL(resolve_pick, dim3(F1B), dim3(256), 0, stream,
                           cand, cnt, idxw, dbest, out, wl, wcount);
        hipLaunchKernelGGL(rescore, dim3(F1B), dim3(256), 0, stream,
                           zt32, key, esq, zsq, cand, cnt, wcount, wl, idxw, dbest, out);
    } else {
        hipLaunchKernelGGL(resolve_fallback, dim3(F1B), dim3(256), 0, stream,
                           z, key, esq, zsq, cand, cnt, out, idxw, dbest);
    }
    hipLaunchKernelGGL(gather, dim3(F2B), dim3(256), 0, stream, val, idxw, out);
    hipLaunchKernelGGL(dsum, dim3(DSB), dim3(256), 0, stream, dbest, partial);
    hipLaunchKernelGGL(fin_kernel, dim3(1), dim3(256), 0, stream, partial, out + ZQV + NTOT);
}

// Round 17
// 376.072 us; speedup vs baseline: 1.7486x; 1.0068x over previous
//
#include <hip/hip_runtime.h>
#include <stdint.h>

constexpr int Cc   = 256;
constexpr int Kc   = 1024;
constexpr int NLOC = 16 * 56 * 56;      // 50176
constexpr int NB   = 2;
constexpr int NTOT = NB * NLOC;         // 100352
constexpr long long ZQV = (long long)NB * Cc * NLOC;  // 25690112

// screen tiling: one block = 128 rows x 128 codes, K=256 in 4 chunks of 64
// (R14/R16-validated geometry: 34.8 KB LDS, ~4 blocks/CU, MfmaUtil ~13%)
constexpr int SR   = 128;
constexpr int SC   = 128;
constexpr int BK   = 64;
constexpr int NCH  = Cc / BK;           // 4
constexpr int NRT  = NTOT / SR;         // 784 row tiles (= 8 XCDs x 98)
constexpr int NSL  = Kc / SC;           // 8
constexpr int SBLK = NRT * NSL;         // 6272

constexpr int   SLOTS = 16;
constexpr float WIN   = 3e-4f;          // validated (absmax idx = 0 at 3e-4)
constexpr float NEG2S = -0.001953125f;  // -2/1024 (exact descale)

constexpr int F1B = NTOT / 256;         // 392
constexpr int RB  = 32;                 // rows per gather block
constexpr int F2B = NTOT / RB;          // 3136

using f16x8 = __attribute__((ext_vector_type(8))) _Float16;
using f32x4 = __attribute__((ext_vector_type(4))) float;
typedef unsigned long long u64;
typedef unsigned int       u32;
typedef unsigned short     u16;

// ---------------------------------------------------------------------------
// numpy-exact helpers (validated, unchanged)
// ---------------------------------------------------------------------------
__device__ __forceinline__ float sqf(float x) {
    float s = x * x;
    asm("" : "+v"(s));
    return s;
}

// numpy pairwise over 128 elements (one half of the 256 reduction):
// 8 accumulators stride-8, tree combine. pw256 == pw128(h0) + pw128(h1).
template <typename Loader>
__device__ __forceinline__ float pw128_sq(Loader ld)
{
    float r[8];
    #pragma unroll
    for (int j = 0; j < 8; ++j) r[j] = sqf(ld(j));
    #pragma unroll
    for (int i = 8; i < 128; i += 8)
        #pragma unroll
        for (int j = 0; j < 8; ++j) r[j] += sqf(ld(i + j));
    return ((r[0] + r[1]) + (r[2] + r[3])) + ((r[4] + r[5]) + (r[6] + r[7]));
}

template <typename Loader>
__device__ __forceinline__ float pw256_sq(Loader ld)
{
    float h0 = pw128_sq([&](int c) { return ld(c); });
    float h1 = pw128_sq([&](int c) { return ld(128 + c); });
    return h0 + h1;
}

__device__ __forceinline__ u16 f16b(float x)
{
    _Float16 h = (_Float16)x;   // v_cvt_f16_f32, RNE
    u16 r;
    __builtin_memcpy(&r, &h, 2);
    return r;
}

// ---------------------------------------------------------------------------
// prep_key: fuses split_e (f16 convert, x1024 exact scale) + esq_pw (numpy-
// pairwise code norms) + cnt/wcount zeroing. Saves 2 dispatches + memset.
// ---------------------------------------------------------------------------
__global__ void prep_key(const float* __restrict__ key, u16* __restrict__ ef16,
                         float* __restrict__ esq,
                         int* __restrict__ cnt, int* __restrict__ wcount)
{
    int i = blockIdx.x * 256 + threadIdx.x;
    if (i < Kc * Cc) ef16[i] = f16b(key[i] * 1024.0f);
    if (i < NTOT) cnt[i] = 0;
    if (i == 0) *wcount = 0;
    if (i < Kc) {
        const float* a = key + (size_t)i * Cc;
        esq[i] = pw256_sq([&](int c) { return a[c]; });
    }
}

// ---------------------------------------------------------------------------
// split_z: z [B][C][NLOC] f32 -> zf16 [NTOT][C] f16 (+ zt32 f32 copy, + zsq).
// NOW two 128-c halves: LDS 33.8 KB -> 4 blocks/CU (was 66.6 KB -> 2).
// zsq = pw128(half0) + pw128(half1) == numpy pw256 bit-exactly.
// ---------------------------------------------------------------------------
__global__ __launch_bounds__(256, 4)
void split_z(const float* __restrict__ z, u16* __restrict__ zf16,
             float* __restrict__ zt32, float* __restrict__ zsq)
{
    __shared__ float t[64][132];   // 33.8 KB
    const int tid = threadIdx.x;
    const int n0  = blockIdx.x * 64;
    const int b   = (n0 >= NLOC) ? 1 : 0;
    const int loc0 = n0 - b * NLOC;
    const float* zb = z + (size_t)b * Cc * NLOC;

    float hs0 = 0.f;   // half-0 sum for row tid (threads < 64)

    #pragma unroll
    for (int h = 0; h < 2; ++h) {
        if (h) __syncthreads();   // phase-2 reads of t done before overwrite
        // phase 1: load c-range [h*128, h*128+128) transposed into t[n][c']
        {
            const int n4 = tid & 15;
            #pragma unroll
            for (int it = 0; it < 2; ++it) {
                int c4 = (tid >> 4) + it * 16;      // 0..31
                int cg = h * 128 + c4 * 4;
                float4 g0 = *reinterpret_cast<const float4*>(zb + (size_t)(cg + 0) * NLOC + loc0 + n4 * 4);
                float4 g1 = *reinterpret_cast<const float4*>(zb + (size_t)(cg + 1) * NLOC + loc0 + n4 * 4);
                float4 g2 = *reinterpret_cast<const float4*>(zb + (size_t)(cg + 2) * NLOC + loc0 + n4 * 4);
                float4 g3 = *reinterpret_cast<const float4*>(zb + (size_t)(cg + 3) * NLOC + loc0 + n4 * 4);
                *reinterpret_cast<float4*>(&t[n4 * 4 + 0][c4 * 4]) = make_float4(g0.x, g1.x, g2.x, g3.x);
                *reinterpret_cast<float4*>(&t[n4 * 4 + 1][c4 * 4]) = make_float4(g0.y, g1.y, g2.y, g3.y);
                *reinterpret_cast<float4*>(&t[n4 * 4 + 2][c4 * 4]) = make_float4(g0.z, g1.z, g2.z, g3.z);
                *reinterpret_cast<float4*>(&t[n4 * 4 + 3][c4 * 4]) = make_float4(g0.w, g1.w, g2.w, g3.w);
            }
        }
        __syncthreads();
        // phase 2: write zf16/zt32 for this half + per-row half-sum
        {
            const int row2 = tid >> 4;          // 0..15
            const int ch   = tid & 15;          // 0..15, 8 c each
            #pragma unroll
            for (int rg = 0; rg < 4; ++rg) {
                int row = rg * 16 + row2;
                float4 f0 = *reinterpret_cast<const float4*>(&t[row][ch * 8]);
                float4 f1 = *reinterpret_cast<const float4*>(&t[row][ch * 8 + 4]);
                float xs[8] = {f0.x, f0.y, f0.z, f0.w, f1.x, f1.y, f1.z, f1.w};
                u32 hp[4];
                #pragma unroll
                for (int j = 0; j < 4; ++j)
                    hp[j] = (u32)f16b(xs[2 * j]) | ((u32)f16b(xs[2 * j + 1]) << 16);
                size_t o = ((size_t)(n0 + row)) * Cc + h * 128 + ch * 8;
                *reinterpret_cast<uint4*>(zf16 + o) = make_uint4(hp[0], hp[1], hp[2], hp[3]);
                if (zt32) {
                    *reinterpret_cast<float4*>(zt32 + o)     = f0;   // bit-exact f32
                    *reinterpret_cast<float4*>(zt32 + o + 4) = f1;
                }
            }
        }
        if (tid < 64) {
            float hv = pw128_sq([&](int c) { return t[tid][c]; });
            if (h == 0) hs0 = hv;
            else        zsq[n0 + tid] = hs0 + hv;   // == numpy pw256 order
        }
    }
}

// global -> LDS direct, 16B/lane (dest = uniform base + lane*16)
__device__ __forceinline__ void gload16(const u16* g, u16* lds)
{
    __builtin_amdgcn_global_load_lds(
        (const __attribute__((address_space(1))) u32*)g,
        (__attribute__((address_space(3))) u32*)lds, 16, 0, 0);
}

// ---------------------------------------------------------------------------
// screen: f16 MFMA GEMM — EXACT R16 code (validated: 166 µs, absmax 0).
// ---------------------------------------------------------------------------
__global__ __launch_bounds__(256, 4)
void screen(const u16* __restrict__ zf16, const u16* __restrict__ ef16,
            const float* __restrict__ esq, const float* __restrict__ zsq,
            u64* __restrict__ cand, int* __restrict__ cnt)
{
    __shared__ u16  A_lds[SR * BK];    // 16 KB
    __shared__ u16  B_lds[SC * BK];    // 16 KB
    __shared__ float gm[2][SR];        // 1 KB
    __shared__ float esq_s[SC];
    __shared__ float zsq_s[SR];

    const int tid = threadIdx.x;
    const int bid = blockIdx.x;
    // XCD grouping: xcd = bid&7 owns row-tiles [xcd*98, (xcd+1)*98)
    const int q   = bid >> 3;
    const int rt  = (bid & 7) * (NRT / 8) + (q >> 3);
    const int r0  = rt * SR;
    const int k0  = (q & 7) * SC;
    const int wid = tid >> 6, l = tid & 63;
    const int wr  = wid >> 1, wc = wid & 1;

    for (int i = tid; i < SC; i += 256) esq_s[i] = esq[k0 + i];
    for (int i = tid; i < SR; i += 256) zsq_s[i] = zsq[r0 + i];

    f32x4 acc[4][4];
    #pragma unroll
    for (int i = 0; i < 4; ++i)
        #pragma unroll
        for (int j = 0; j < 4; ++j)
            acc[i][j] = f32x4{0.f, 0.f, 0.f, 0.f};

    for (int ch = 0; ch < NCH; ++ch) {
        __syncthreads();   // previous chunk consumed (covers esq_s/zsq_s on ch=0)
        {
            const int lr = l >> 3;
            #pragma unroll
            for (int t = 0; t < 4; ++t) {
                int rowb = wid * 32 + t * 8;
                int row  = rowb + lr;
                int g    = (l & 7) ^ (row & 7);
                gload16(zf16 + (size_t)(r0 + row) * Cc + ch * BK + g * 8,
                        A_lds + rowb * BK);
                gload16(ef16 + (size_t)(k0 + row) * Cc + ch * BK + g * 8,
                        B_lds + rowb * BK);
            }
        }
        __syncthreads();   // vmcnt drained

        #pragma unroll
        for (int kk = 0; kk < 2; ++kk) {
            f16x8 af[4], bf[4];
            const int G = kk * 4 + (l >> 4);
            #pragma unroll
            for (int i = 0; i < 4; ++i) {
                int row = wr * 64 + i * 16 + (l & 15);
                int pg  = G ^ (row & 7);
                af[i] = *reinterpret_cast<const f16x8*>(&A_lds[row * BK + pg * 8]);
            }
            #pragma unroll
            for (int j = 0; j < 4; ++j) {
                int col = wc * 64 + j * 16 + (l & 15);
                int pg  = G ^ (col & 7);
                bf[j] = *reinterpret_cast<const f16x8*>(&B_lds[col * BK + pg * 8]);
            }
            #pragma unroll
            for (int i = 0; i < 4; ++i)
                #pragma unroll
                for (int j = 0; j < 4; ++j)
                    acc[i][j] = __builtin_amdgcn_mfma_f32_16x16x32_f16(
                        af[i], bf[j], acc[i][j], 0, 0, 0);
        }
    }

    // ---- epilogue pass 1: f32 slice-min per row ----
    #pragma unroll
    for (int i = 0; i < 4; ++i) {
        #pragma unroll
        for (int r = 0; r < 4; ++r) {
            int rloc = wr * 64 + i * 16 + ((l >> 4) << 2) + r;
            float zq = zsq_s[rloc];
            float mn = 3.4e38f;
            #pragma unroll
            for (int j = 0; j < 4; ++j) {
                int cl = wc * 64 + j * 16 + (l & 15);
                float d = fmaf(NEG2S, acc[i][j][r], zq + esq_s[cl]);
                mn = fminf(mn, d);
            }
            #pragma unroll
            for (int m = 1; m < 16; m <<= 1)
                mn = fminf(mn, __shfl_xor(mn, m, 64));
            if ((l & 15) == 0) gm[wc][rloc] = mn;
        }
    }
    __syncthreads();

    // ---- epilogue pass 2: window emission ----
    #pragma unroll
    for (int i = 0; i < 4; ++i) {
        #pragma unroll
        for (int r = 0; r < 4; ++r) {
            int rloc = wr * 64 + i * 16 + ((l >> 4) << 2) + r;
            float thr = fminf(gm[0][rloc], gm[1][rloc]) + WIN;
            float zq = zsq_s[rloc];
            int rg = r0 + rloc;
            #pragma unroll
            for (int j = 0; j < 4; ++j) {
                int cl = wc * 64 + j * 16 + (l & 15);
                float d = fmaf(NEG2S, acc[i][j][r], zq + esq_s[cl]);
                if (d <= thr) {
                    int slot = atomicAdd(&cnt[rg], 1);
                    if (slot < SLOTS)
                        cand[(size_t)rg * SLOTS + slot] =
                            ((u64)__float_as_uint(d) << 32) | (u32)(k0 + cl);
                }
            }
        }
    }
}

// ---------------------------------------------------------------------------
// resolve_pick: thread per row; best candidate + dbest (= loss term);
// ambiguous/overflow rows -> worklist.
// ---------------------------------------------------------------------------
__global__ __launch_bounds__(256)
void resolve_pick(const u64* __restrict__ cand, const int* __restrict__ cnt,
                  int* __restrict__ idxw, float* __restrict__ dbest,
                  float* __restrict__ out,
                  int* __restrict__ wl, int* __restrict__ wcount)
{
    const int p = blockIdx.x * 256 + threadIdx.x;
    const int c = cnt[p];
    const int n = (c < SLOTS) ? c : SLOTS;
    u64 best = 0xFFFFFFFFFFFFFFFFull;
    for (int s = 0; s < n; ++s) {
        u64 v = cand[(size_t)p * SLOTS + s];
        if (v < best) best = v;
    }
    const float db = __uint_as_float((u32)(best >> 32));

    bool needs = (c > SLOTS);
    if (!needs) {
        int namb = 0;
        for (int s = 0; s < n; ++s) {
            float dv = __uint_as_float((u32)(cand[(size_t)p * SLOTS + s] >> 32));
            namb += (dv <= db + WIN) ? 1 : 0;
        }
        needs = (namb > 1);
    }
    if (needs) wl[atomicAdd(wcount, 1)] = p;

    idxw[p] = (int)(u32)best;
    dbest[p] = db;                      // d == ||key[k]-z||^2 (validated R15/R16)
    out[ZQV + p] = (float)(u32)best;
}

// ---------------------------------------------------------------------------
// rescore: np-exact re-evaluation of worklist rows using contiguous zt32 rows.
// ---------------------------------------------------------------------------
__global__ __launch_bounds__(256)
void rescore(const float* __restrict__ zt32, const float* __restrict__ key,
             const float* __restrict__ esq, const float* __restrict__ zsq,
             const u64* __restrict__ cand, const int* __restrict__ cnt,
             const int* __restrict__ wcount, const int* __restrict__ wl,
             int* __restrict__ idxw, float* __restrict__ dbest,
             float* __restrict__ out)
{
    const int i = blockIdx.x * 256 + threadIdx.x;
    if (i >= *wcount) return;
    const int p = wl[i];
    const float* zr = zt32 + (size_t)p * Cc;   // bit-exact f32 z row
    const float zq = zsq[p];
    const int c = cnt[p];
    u64 bb = 0xFFFFFFFFFFFFFFFFull;

    if (c > SLOTS) {
        for (int k = 0; k < Kc; ++k) {
            const float* kr = key + (size_t)k * Cc;
            float m = 0.f;
            for (int cc = 0; cc < Cc; ++cc)
                m = fmaf(zr[cc], kr[cc], m);
            float d = fmaf(-2.0f, m, zq + esq[k]);
            u64 pk = ((u64)__float_as_uint(d) << 32) | (u32)k;
            if (pk < bb) bb = pk;
        }
    } else {
        u64 best = 0xFFFFFFFFFFFFFFFFull;
        for (int s = 0; s < c; ++s) {
            u64 v = cand[(size_t)p * SLOTS + s];
            if (v < best) best = v;
        }
        const float db = __uint_as_float((u32)(best >> 32));
        for (int s = 0; s < c; ++s) {
            u64 v = cand[(size_t)p * SLOTS + s];
            float dv = __uint_as_float((u32)(v >> 32));
            if (dv <= db + WIN) {
                int k = (int)(u32)v;
                const float* kr = key + (size_t)k * Cc;
                float m = 0.f;
                for (int cc = 0; cc < Cc; ++cc)
                    m = fmaf(zr[cc], kr[cc], m);
                float d = fmaf(-2.0f, m, zq + esq[k]);
                u64 pk = ((u64)__float_as_uint(d) << 32) | (u32)k;
                if (pk < bb) bb = pk;
            }
        }
    }
    idxw[p] = (int)(u32)bb;
    dbest[p] = __uint_as_float((u32)(bb >> 32));
    out[ZQV + p] = (float)(u32)bb;
}

// ---------------------------------------------------------------------------
// resolve_fallback: monolithic path (strided z reads) if ws too small for zt32
// ---------------------------------------------------------------------------
__global__ __launch_bounds__(256)
void resolve_fallback(const float* __restrict__ z, const float* __restrict__ key,
                      const float* __restrict__ esq, const float* __restrict__ zsq,
                      const u64* __restrict__ cand, const int* __restrict__ cnt,
                      float* __restrict__ out, int* __restrict__ idxw,
                      float* __restrict__ dbest)
{
    const int p   = blockIdx.x * 256 + threadIdx.x;
    const int b   = (p >= NLOC) ? 1 : 0;
    const int loc = p - b * NLOC;
    const float* zb = z + (size_t)b * Cc * NLOC;

    const int c = cnt[p];
    const int n = (c < SLOTS) ? c : SLOTS;
    u64 best = 0xFFFFFFFFFFFFFFFFull;
    for (int s = 0; s < n; ++s) {
        u64 v = cand[(size_t)p * SLOTS + s];
        if (v < best) best = v;
    }
    u64 sel = best;
    const float db = __uint_as_float((u32)(best >> 32));

    if (c > SLOTS) {
        u64 bb = 0xFFFFFFFFFFFFFFFFull;
        for (int k = 0; k < Kc; ++k) {
            const float* kr = key + (size_t)k * Cc;
            float m = 0.f;
            for (int cc = 0; cc < Cc; ++cc)
                m = fmaf(zb[(size_t)cc * NLOC + loc], kr[cc], m);
            float d = fmaf(-2.0f, m, zsq[p] + esq[k]);
            u64 pk = ((u64)__float_as_uint(d) << 32) | (u32)k;
            if (pk < bb) bb = pk;
        }
        sel = bb;
    } else {
        int namb = 0;
        for (int s = 0; s < n; ++s) {
            float dv = __uint_as_float((u32)(cand[(size_t)p * SLOTS + s] >> 32));
            namb += (dv <= db + WIN) ? 1 : 0;
        }
        if (namb > 1) {
            u64 bb = 0xFFFFFFFFFFFFFFFFull;
            for (int s = 0; s < n; ++s) {
                u64 v = cand[(size_t)p * SLOTS + s];
                float dv = __uint_as_float((u32)(v >> 32));
                if (dv <= db + WIN) {
                    int k = (int)(u32)v;
                    const float* kr = key + (size_t)k * Cc;
                    float m = 0.f;
                    for (int cc = 0; cc < Cc; ++cc)
                        m = fmaf(zb[(size_t)cc * NLOC + loc], kr[cc], m);
                    float d = fmaf(-2.0f, m, zsq[p] + esq[k]);
                    u64 pk = ((u64)__float_as_uint(d) << 32) | (u32)k;
                    if (pk < bb) bb = pk;
                }
            }
            sel = bb;
        }
    }
    idxw[p] = (int)(u32)sel;
    dbest[p] = __uint_as_float((u32)(sel >> 32));
    out[ZQV + p] = (float)(u32)sel;
}

// ---------------------------------------------------------------------------
// gather: val-row gather + z_q_value write + fused dbest partial (dsum).
// ---------------------------------------------------------------------------
__global__ __launch_bounds__(256)
void gather(const float* __restrict__ val, const int* __restrict__ idxw,
            const float* __restrict__ dbest,
            float* __restrict__ out, double* __restrict__ partial)
{
    __shared__ float rowbuf[RB][261];
    __shared__ int   idx_sh[RB];
    const int tid = threadIdx.x, blk = blockIdx.x;
    const int wid = tid >> 6, l = tid & 63;
    const int p0  = blk * RB;
    const int b   = (p0 >= NLOC) ? 1 : 0;
    const int loc0 = p0 - b * NLOC;

    if (tid < RB) idx_sh[tid] = idxw[p0 + tid];

    // fused dsum: wave 0 sums the block's 32 dbest values (deterministic)
    if (tid < 64) {
        double s = (tid < RB) ? (double)dbest[p0 + tid] : 0.0;
        for (int off = 32; off > 0; off >>= 1) s += __shfl_down(s, off);
        if (tid == 0) partial[blk] = s;
    }
    __syncthreads();

    #pragma unroll
    for (int i = 0; i < RB / 4; ++i) {
        int row = wid * (RB / 4) + i;
        float4 v = *reinterpret_cast<const float4*>(val + (size_t)idx_sh[row] * Cc + l * 4);
        *reinterpret_cast<float4*>(&rowbuf[row][l * 4]) = v;
    }
    __syncthreads();

    const int nq = l & 7;
    #pragma unroll
    for (int it = 0; it < 8; ++it) {
        int cc = (l >> 3) + 8 * it + 64 * wid;
        float4 v = make_float4(rowbuf[nq * 4 + 0][cc], rowbuf[nq * 4 + 1][cc],
                               rowbuf[nq * 4 + 2][cc], rowbuf[nq * 4 + 3][cc]);
        *reinterpret_cast<float4*>(
            out + ((size_t)b * Cc + cc) * NLOC + loc0 + nq * 4) = v;
    }
}

__global__ void fin_kernel(const double* __restrict__ partial, float* __restrict__ out_loss)
{
    __shared__ double sh[256];
    double s = 0.0;
    for (int i = threadIdx.x; i < F2B; i += 256) s += partial[i];
    sh[threadIdx.x] = s;
    __syncthreads();
    for (int st = 128; st > 0; st >>= 1) {
        if (threadIdx.x < st) sh[threadIdx.x] += sh[threadIdx.x + st];
        __syncthreads();
    }
    if (threadIdx.x == 0)
        out_loss[0] = (float)(1.25 * sh[0] / (double)((long long)NTOT * Cc));
}

// ---------------------------------------------------------------------------
extern "C" void kernel_launch(void* const* d_in, const int* in_sizes, int n_in,
                              void* d_out, int out_size, void* d_ws, size_t ws_size,
                              hipStream_t stream)
{
    const float* z   = (const float*)d_in[0];
    const float* key = (const float*)d_in[1];
    const float* val = (const float*)d_in[2];
    float* out = (float*)d_out;

    // zf16 scratch lives in the z_q_value output region (dead before gather)
    u16* zf16 = (u16*)d_out;

    char* w = (char*)d_ws;
    u16*    ef16    = (u16*)w;                 w += (size_t)Kc * Cc * 2;        // 512 KB
    u64*    cand    = (u64*)w;                 w += (size_t)NTOT * SLOTS * 8;   // 12.85 MB
    int*    cnt     = (int*)w;                 w += (size_t)NTOT * 4;           // 401 KB
    int*    wcount  = (int*)w;                 w += 16;
    int*    idxw    = (int*)w;                 w += (size_t)NTOT * 4;
    int*    wl      = (int*)w;                 w += (size_t)NTOT * 4;
    float*  dbest   = (float*)w;               w += (size_t)NTOT * 4;
    double* partial = (double*)w;              w += (size_t)F2B * 8;
    float*  esq     = (float*)w;               w += (size_t)Kc * 4;
    float*  zsq     = (float*)w;               w += (size_t)NTOT * 4;
    float*  zt32    = (float*)w;
    size_t  need_big = (size_t)(w - (char*)d_ws) + (size_t)NTOT * Cc * 4;
    const bool big = ws_size >= need_big;

    hipLaunchKernelGGL(prep_key, dim3((Kc * Cc + 255) / 256), dim3(256), 0, stream,
                       key, ef16, esq, cnt, wcount);
    hipLaunchKernelGGL(split_z, dim3(NTOT / 64), dim3(256), 0, stream, z, zf16,
                       big ? zt32 : (float*)nullptr, zsq);
    hipLaunchKernelGGL(screen, dim3(SBLK), dim3(256), 0, stream,
                       zf16, ef16, esq, zsq, cand, cnt);
    if (big) {
        hipLaunchKernelGGL(resolve_pick, dim3(F1B), dim3(256), 0, stream,
                           cand, cnt, idxw, dbest, out, wl, wcount);
        hipLaunchKernelGGL(rescore, dim3(F1B), dim3(256), 0, stream,
                           zt32, key, esq, zsq, cand, cnt, wcount, wl, idxw, dbest, out);
    } else {
        hipLaunchKernelGGL(resolve_fallback, dim3(F1B), dim3(256), 0, stream,
                           z, key, esq, zsq, cand, cnt, out, idxw, dbest);
    }
    hipLaunchKernelGGL(gather, dim3(F2B), dim3(256), 0, stream,
                       val, idxw, dbest, out, partial);
    hipLaunchKernelGGL(fin_kernel, dim3(1), dim3(256), 0, stream, partial, out + ZQV + NTOT);
}